// Round 6
// baseline (234.610 us; speedup 1.0000x reference)
//
#include <hip/hip_runtime.h>

#define BINS 25
#define H 512
#define W 512
#define NPLANES 96   // B*C = 32*3
#define TOX 32       // output tile width
#define TOY 16       // output tile height
#define TROWS 37     // input rows per tile: 2*16+5
#define RP 72        // raw pitch (floats) = 18 float4; slot v <-> raw[4*v]
#define NV4 (TROWS*18)   // 666 float4 per tile
#define VP 36        // ve/vo pitch
#define NSH 16       // sub-histograms
#define TPB 8        // tiles per block (half a column band)
#define NBANDS (2*NPLANES*8*2)   // 192 planes * 8 x-bands * 2 halves = 3072

// Block = 256 threads; processes 8 vertically-adjacent 32x16 output tiles of
// one plane (software-pipelined: global->regs for tile k+1 overlaps compute
// of tile k). grid = NBANDS.
__global__ __launch_bounds__(256) void blur_hist(
        const float* __restrict__ x, const float* __restrict__ y,
        unsigned int* __restrict__ partial) {
    const int band = blockIdx.x;
    const int z    = band >> 4;           // 0..191
    const int r16  = band & 15;
    const int bx   = r16 >> 1;            // x-band 0..7
    const int ty0  = (r16 & 1) * TPB;     // tile row start: 0 or 8

    const float* src = (z < NPLANES) ? x + (size_t)z * H * W
                                     : y + (size_t)(z - NPLANES) * H * W;

    __shared__ __align__(16) float raw[TROWS * RP];        // 10.65 KB
    __shared__ __align__(16) float ve[TOY * VP];
    __shared__ __align__(16) float vo[TOY * VP];
    __shared__ __align__(16) unsigned int sh[NSH * BINS];  // 1.6 KB

    const int tid = threadIdx.x;
    const int base_x = 64 * bx - 4;

    if (tid < 100) *(float4*)((float*)sh + 4 * tid) = make_float4(0.f, 0.f, 0.f, 0.f);

    // ---- per-thread prefetch slot geometry (tile-invariant) ----
    int rr[3], off[3];
    bool ld[3];   // do the global load (in-range slot and x-in-bounds quad)
    #pragma unroll
    for (int k = 0; k < 3; k++) {
        int v = tid + 256 * k;
        int r = v / 18;
        int c4 = v - 18 * r;
        rr[k]  = r;
        off[k] = r * W + base_x + 4 * c4;
        bool inr  = (v < NV4);
        bool xoob = (bx == 0 && c4 == 0) || (bx == 7 && c4 == 17);
        ld[k] = inr && !xoob;   // xoob quads stay zero (padding)
    }

    float4 P[3];
    auto loadtile = [&](int T) {
        const ptrdiff_t tb = (ptrdiff_t)(32 * T - 3) * W;
        const bool ychk = (T == 0) || (T == 15);
        #pragma unroll
        for (int k = 0; k < 3; k++) {
            float4 v4 = make_float4(0.f, 0.f, 0.f, 0.f);
            if (ld[k]) {
                if (ychk) {
                    int gy = 32 * T - 3 + rr[k];
                    if (gy >= 0 && gy < H) v4 = *(const float4*)(src + tb + off[k]);
                } else {
                    v4 = *(const float4*)(src + tb + off[k]);
                }
            }
            P[k] = v4;
        }
    };
    auto writeraw = [&]() {   // slot v -> raw[4v]; lanes consecutive: conflict-free
        *(float4*)(raw + 4 * (tid + 0))   = P[0];
        *(float4*)(raw + 4 * (tid + 256)) = P[1];
        if (tid < NV4 - 512) *(float4*)(raw + 4 * (tid + 512)) = P[2];
    };

    const float w0 = 1.f/64.f, w1 = 6.f/64.f, w2 = 15.f/64.f, w3 = 20.f/64.f;

    // ---- stage2 geometry (tile-invariant): 288 tasks, 4 cols/task ----
    const int ly_a = tid / 18, q_a = tid - 18 * ly_a;
    const int vb = tid + 256;
    const int ly_b = vb / 18, q_b = vb - 18 * ly_b;   // valid when tid < 32

    auto vpass = [&](int ly, int q) {
        const float* p = raw + (2 * ly) * RP + 4 * q;
        float4 a0 = *(const float4*)(p + 0 * RP);
        float4 a1 = *(const float4*)(p + 1 * RP);
        float4 a2 = *(const float4*)(p + 2 * RP);
        float4 a3 = *(const float4*)(p + 3 * RP);
        float4 a4 = *(const float4*)(p + 4 * RP);
        float4 a5 = *(const float4*)(p + 5 * RP);
        float4 a6 = *(const float4*)(p + 6 * RP);
        float s0 = w0*(a0.x+a6.x) + w1*(a1.x+a5.x) + w2*(a2.x+a4.x) + w3*a3.x;
        float s1 = w0*(a0.y+a6.y) + w1*(a1.y+a5.y) + w2*(a2.y+a4.y) + w3*a3.y;
        float s2 = w0*(a0.z+a6.z) + w1*(a1.z+a5.z) + w2*(a2.z+a4.z) + w3*a3.z;
        float s3 = w0*(a0.w+a6.w) + w1*(a1.w+a5.w) + w2*(a2.w+a4.w) + w3*a3.w;
        *(float2*)(ve + ly * VP + 2 * q) = make_float2(s0, s2);
        *(float2*)(vo + ly * VP + 2 * q) = make_float2(s1, s3);
    };
    auto stage2 = [&]() {
        vpass(ly_a, q_a);
        if (tid < 32) vpass(ly_b, q_b);
    };

    // ---- stage3 geometry: 128 threads, 4 consecutive outputs each ----
    const int ly3 = tid >> 3;
    const int qq  = tid & 7;
    unsigned int* wh = sh + (tid & (NSH - 1)) * BINS;
    auto stage3 = [&]() {
        if (tid < 128) {
            const float* ob = vo + ly3 * VP + 4 * qq;
            const float* eb = ve + ly3 * VP + 4 * qq;
            float4 A = *(const float4*)(ob);
            float4 B = *(const float4*)(ob + 4);
            float4 C = *(const float4*)(eb);
            float4 D = *(const float4*)(eb + 4);
            float oa[8] = {A.x, A.y, A.z, A.w, B.x, B.y, B.z, B.w};
            float ea[8] = {C.x, C.y, C.z, C.w, D.x, D.y, D.z, D.w};
            #pragma unroll
            for (int j = 0; j < 4; j++) {
                float s = w0*(oa[j] + oa[j+3]) + w2*(oa[j+1] + oa[j+2])
                        + w1*(ea[j+1] + ea[j+3]) + w3*ea[j+2];
                int b = min((int)(s * 25.f), BINS - 1);   // s in [0,1]
                atomicAdd(&wh[b], 1u);
            }
        }
    };

    // ---- software-pipelined tile loop ----
    loadtile(ty0);
    writeraw();
    __syncthreads();                       // raw = tile ty0; sh zeroed
    #pragma unroll 1
    for (int i = 0; i < TPB - 1; i++) {
        loadtile(ty0 + i + 1);             // global loads in flight ...
        stage2();                          // ... hidden behind LDS compute
        __syncthreads();                   // raw reads done; ve/vo ready
        stage3();
        writeraw();                        // vmcnt wait lands here
        __syncthreads();                   // raw = next tile; ve/vo reads done
    }
    stage2();
    __syncthreads();
    stage3();
    __syncthreads();

    // ---- one histogram writeout per band ----
    if (tid < BINS) {
        unsigned int s = 0;
        #pragma unroll
        for (int g = 0; g < NSH; g++) s += sh[g * BINS + tid];
        partial[band * BINS + tid] = s;
    }
}

// 96 blocks x 64 threads: plane p gathers its 16 x-band partials for x and y,
// cosine sim, atomic mean into out[0].
__global__ __launch_bounds__(64) void reduce_cos(
        const unsigned int* __restrict__ partial, float* __restrict__ out) {
    __shared__ float sa[BINS], sb[BINS];
    const int p = blockIdx.x;
    const int t = threadIdx.x;
    if (t < BINS) {
        unsigned int a = 0, b = 0;
        #pragma unroll
        for (int j = 0; j < 16; j++) {
            a += partial[((size_t)(p) * 16 + j) * BINS + t];
            b += partial[((size_t)(NPLANES + p) * 16 + j) * BINS + t];
        }
        sa[t] = (float)a;
        sb[t] = (float)b;
    }
    __syncthreads();
    if (t == 0) {
        const float inv_hw = 1.0f / (float)(H * W);
        float dot = 0.f, nx = 0.f, ny = 0.f;
        for (int i = 0; i < BINS; i++) {
            float a = sa[i] * inv_hw;
            float b = sb[i] * inv_hw;
            dot += a * b;
            nx  += a * a;
            ny  += b * b;
        }
        nx = fmaxf(sqrtf(nx), 1e-6f);
        ny = fmaxf(sqrtf(ny), 1e-6f);
        atomicAdd(out, (dot / (nx * ny)) * (1.0f / (float)NPLANES));
    }
}

extern "C" void kernel_launch(void* const* d_in, const int* in_sizes, int n_in,
                              void* d_out, int out_size, void* d_ws, size_t ws_size,
                              hipStream_t stream) {
    const float* x = (const float*)d_in[0];
    const float* y = (const float*)d_in[1];
    float* out = (float*)d_out;

    unsigned int* partial = (unsigned int*)d_ws;   // [NBANDS][BINS] = 300 KB

    hipMemsetAsync(out, 0, sizeof(float), stream);

    blur_hist<<<NBANDS, 256, 0, stream>>>(x, y, partial);
    reduce_cos<<<NPLANES, 64, 0, stream>>>(partial, out);
}

// Round 7
// 219.403 us; speedup vs baseline: 1.0693x; 1.0693x over previous
//
#include <hip/hip_runtime.h>

#define BINS 25
#define H 512
#define W 512
#define NPLANES 96   // B*C = 32*3
#define NSH 32       // sub-histograms per block

// Block = 256 threads = 4 waves; block b covers plane z = b>>2, y-strips
// 4*(b&3) .. 4*(b&3)+3 (one 16-output-row strip per wave).
// Thread: x-lane i = tid&63 owns output cols 4i..4i+3; walks 16 output rows.
// No barriers in the walk: 7-row register window of h-blurred float4s.
__global__ __launch_bounds__(256) void blur_hist(
        const float* __restrict__ x, const float* __restrict__ y,
        unsigned int* __restrict__ partial) {
    const int b = blockIdx.x;
    const int z = b >> 2;
    const float* src = (z < NPLANES) ? x + (size_t)z * H * W
                                     : y + (size_t)(z - NPLANES) * H * W;

    __shared__ unsigned int sh[NSH * BINS];   // 3.2 KB
    const int tid = threadIdx.x;
    if (tid < (NSH * BINS / 4))
        *(float4*)((float*)sh + 4 * tid) = make_float4(0.f, 0.f, 0.f, 0.f);
    __syncthreads();

    const int i = tid & 63;                   // x-lane
    const int s = (b & 3) * 4 + (tid >> 6);   // y-strip 0..15 (wave-uniform)
    const int c0 = 8 * i - 4;                 // col of quad0
    const int o0 = (i == 0)  ? 0   : c0;      // clamped quad0 col
    const int o3 = (i == 63) ? 508 : c0 + 12; // clamped quad3 col
    const float m0 = (i == 0)  ? 0.f : 1.f;   // zero-mask for left halo
    const float m3 = (i == 63) ? 0.f : 1.f;   // zero-mask for right halo

    const float w0 = 1.f/64.f, w1 = 6.f/64.f, w2 = 15.f/64.f, w3 = 20.f/64.f;

    // load input row gy, horizontal 7-tap blur (stride 2) for 4 output cols
    auto load_row = [&](int gy) -> float4 {
        float4 h = make_float4(0.f, 0.f, 0.f, 0.f);
        if ((unsigned)gy < (unsigned)H) {     // wave-uniform branch
            const float* rp = src + (size_t)gy * W;
            float4 Q0 = *(const float4*)(rp + o0);
            float4 Q1 = *(const float4*)(rp + c0 + 4);
            float4 Q2 = *(const float4*)(rp + c0 + 8);
            float4 Q3 = *(const float4*)(rp + o3);
            float r1 = Q0.y * m0, r2 = Q0.z * m0, r3 = Q0.w * m0;
            float r4 = Q1.x, r5 = Q1.y, r6 = Q1.z, r7 = Q1.w;
            float r8 = Q2.x, r9 = Q2.y, r10 = Q2.z, r11 = Q2.w;
            float r12 = Q3.x * m3, r13 = Q3.y * m3;
            h.x = w0*(r1 + r7)  + w1*(r2 + r6)  + w2*(r3 + r5)  + w3*r4;
            h.y = w0*(r3 + r9)  + w1*(r4 + r8)  + w2*(r5 + r7)  + w3*r6;
            h.z = w0*(r5 + r11) + w1*(r6 + r10) + w2*(r7 + r9)  + w3*r8;
            h.w = w0*(r7 + r13) + w1*(r8 + r12) + w2*(r9 + r11) + w3*r10;
        }
        return h;
    };

    unsigned int* wh = sh + (tid & (NSH - 1)) * BINS;
    auto binit = [&](float v) {
        int bb = min((int)(v * 25.f), BINS - 1);   // v in [0,1] by construction
        atomicAdd(&wh[bb], 1u);
    };
    auto vout = [&](const float4& h0, const float4& h1, const float4& h2,
                    const float4& h3, const float4& h4, const float4& h5,
                    const float4& h6) {
        binit(w0*(h0.x+h6.x) + w1*(h1.x+h5.x) + w2*(h2.x+h4.x) + w3*h3.x);
        binit(w0*(h0.y+h6.y) + w1*(h1.y+h5.y) + w2*(h2.y+h4.y) + w3*h3.y);
        binit(w0*(h0.z+h6.z) + w1*(h1.z+h5.z) + w2*(h2.z+h4.z) + w3*h3.z);
        binit(w0*(h0.w+h6.w) + w1*(h1.w+h5.w) + w2*(h2.w+h4.w) + w3*h3.w);
    };

    // ---- register-window walk: rows 2oy-3..2oy+3 live as h0..h6 ----
    const int gy0 = 32 * s - 3;
    float4 h0 = load_row(gy0 + 0), h1 = load_row(gy0 + 1), h2 = load_row(gy0 + 2),
           h3 = load_row(gy0 + 3), h4 = load_row(gy0 + 4), h5 = load_row(gy0 + 5),
           h6 = load_row(gy0 + 6);
    #pragma unroll 5
    for (int j = 0; j < 15; j++) {
        float4 hA = load_row(gy0 + 7 + 2 * j);   // next-iter rows: loads in
        float4 hB = load_row(gy0 + 8 + 2 * j);   // flight over compute below
        vout(h0, h1, h2, h3, h4, h5, h6);
        h0 = h2; h1 = h3; h2 = h4; h3 = h5; h4 = h6; h5 = hA; h6 = hB;
    }
    vout(h0, h1, h2, h3, h4, h5, h6);
    __syncthreads();

    // ---- one histogram writeout per block ----
    if (tid < BINS) {
        unsigned int acc = 0;
        #pragma unroll
        for (int g = 0; g < NSH; g++) acc += sh[g * BINS + tid];
        partial[b * BINS + tid] = acc;
    }
}

// 96 blocks x 64 threads: plane p gathers its 4 block-partials for x and y,
// cosine sim, atomic mean into out[0].
__global__ __launch_bounds__(64) void reduce_cos(
        const unsigned int* __restrict__ partial, float* __restrict__ out) {
    __shared__ float sa[BINS], sb[BINS];
    const int p = blockIdx.x;
    const int t = threadIdx.x;
    if (t < BINS) {
        unsigned int a = 0, bb = 0;
        #pragma unroll
        for (int j = 0; j < 4; j++) {
            a  += partial[((size_t)p * 4 + j) * BINS + t];
            bb += partial[((size_t)(NPLANES + p) * 4 + j) * BINS + t];
        }
        sa[t] = (float)a;
        sb[t] = (float)bb;
    }
    __syncthreads();
    if (t == 0) {
        const float inv_hw = 1.0f / (float)(H * W);
        float dot = 0.f, nx = 0.f, ny = 0.f;
        for (int k = 0; k < BINS; k++) {
            float a = sa[k] * inv_hw;
            float c = sb[k] * inv_hw;
            dot += a * c;
            nx  += a * a;
            ny  += c * c;
        }
        nx = fmaxf(sqrtf(nx), 1e-6f);
        ny = fmaxf(sqrtf(ny), 1e-6f);
        atomicAdd(out, (dot / (nx * ny)) * (1.0f / (float)NPLANES));
    }
}

extern "C" void kernel_launch(void* const* d_in, const int* in_sizes, int n_in,
                              void* d_out, int out_size, void* d_ws, size_t ws_size,
                              hipStream_t stream) {
    const float* x = (const float*)d_in[0];
    const float* y = (const float*)d_in[1];
    float* out = (float*)d_out;

    unsigned int* partial = (unsigned int*)d_ws;   // [768][25] u32 = 76.8 KB

    hipMemsetAsync(out, 0, sizeof(float), stream);

    blur_hist<<<768, 256, 0, stream>>>(x, y, partial);
    reduce_cos<<<NPLANES, 64, 0, stream>>>(partial, out);
}